// Round 13
// baseline (7331.851 us; speedup 1.0000x reference)
//
#include <hip/hip_runtime.h>
#include <hip/hip_bf16.h>
#include <math.h>

#define NM   128
#define PAD  132   // f32 LDS pitch
#define PB   136   // u16 LDS pitch for MFMA bf16 splits
#define PBI  144   // i8 plane pitch (bytes)

typedef __attribute__((ext_vector_type(8))) short bf16x8;
typedef __attribute__((ext_vector_type(4))) float f32x4;
typedef __attribute__((ext_vector_type(4))) int   i32x4;

// ============================================================================
// log(A) = ln(s) I + 8 * cheb_log( NS_sqrt^3( A/s ) ).
// Round-13: round-12's i8 path never LAUNCHED (__has_builtin guard is false in
// the HOST pass -> host chose ns_tri4; counters proved it). Guard removed —
// the i8 MFMA builtin is HW-verified on gfx950. Algorithm unchanged:
// first 4 NS iters in EXACT 24-bit fixed-point i8-MFMA (quantize round(x*2^21),
// 3 i8 planes, 8 products in 4 weight-grouped exact i32 accumulators).
// Invariants: every matrix written is EXACTLY symmetric (mirror-write +
// symdiag-on-full-output); passthroughs read LDS-resident data only.
// ============================================================================

// ---------------------------------------------------------------- f32 kernels
__global__ __launch_bounds__(256,1)
void scale_kernel(const float* __restrict__ A, float* __restrict__ outY,
                  float* __restrict__ outM, float* __restrict__ lns)
{
    __shared__ __align__(16) float L[NM][PAD];
    __shared__ float rs[NM];
    __shared__ float s_inv;
    const int t = threadIdx.x;
    const long long b = blockIdx.x;
    const long long off = b << 14;
    for (int v = 0; v < 16; ++v) {
        int f = t + v*256;
        int row = f >> 5, c4 = (f & 31) << 2;
        *(float4*)&L[row][c4] = ((const float4*)(A + off))[f];
    }
    __syncthreads();
    if (t < NM) {
        float s = 0.f;
        for (int j = 0; j < NM; ++j) s += fabsf(L[t][j]);
        rs[t] = s;
    }
    __syncthreads();
    if (t < 64) {
        float m = fmaxf(rs[t], rs[t+64]);
        #pragma unroll
        for (int o = 32; o > 0; o >>= 1) m = fmaxf(m, __shfl_down(m, o, 64));
        if (t == 0) { s_inv = 1.0f/m; lns[b] = logf(m); }
    }
    __syncthreads();
    const float inv = s_inv;
    for (int v = 0; v < 16; ++v) {
        int f = t + v*256;
        int row = f >> 5, c4 = (f & 31) << 2;
        float4 x = *(const float4*)&L[row][c4];
        x.x *= inv; x.y *= inv; x.z *= inv; x.w *= inv;
        ((float4*)(outY + off))[f] = x;
        ((float4*)(outM + off))[f] = x;
    }
}

__global__ __launch_bounds__(256,1)
void rescale_kernel(const float* __restrict__ Sq, float* __restrict__ X,
                    float* __restrict__ M, float* __restrict__ lns)
{
    __shared__ __align__(16) float L[NM][PAD];
    __shared__ float rs[NM];
    __shared__ float s_g;
    const int t = threadIdx.x;
    const long long b = blockIdx.x;
    const long long off = b << 14;
    for (int v = 0; v < 16; ++v) {
        int f = t + v*256;
        int row = f >> 5, c4 = (f & 31) << 2;
        *(float4*)&L[row][c4] = ((const float4*)(Sq + off))[f];
    }
    __syncthreads();
    if (t < NM) {
        float s = 0.f;
        for (int j = 0; j < NM; ++j) s += fabsf(L[t][j]);
        rs[t] = s;
    }
    __syncthreads();
    if (t < 64) {
        float m = fmaxf(rs[t], rs[t+64]);
        #pragma unroll
        for (int o = 32; o > 0; o >>= 1) m = fmaxf(m, __shfl_down(m, o, 64));
        if (t == 0) { s_g = 1.0f/sqrtf(m); lns[b] = lns[b] + 0.5f*logf(m); }
    }
    __syncthreads();
    const float g = s_g;
    for (int v = 0; v < 16; ++v) {
        int f = t + v*256;
        float4 x = ((const float4*)(X + off))[f];
        x.x *= g; x.y *= g; x.z *= g; x.w *= g;
        ((float4*)(X + off))[f] = x;
        ((float4*)(M + off))[f] = x;
    }
}

// triangular index decode: u -> (bi,bj), bj<=bi
__device__ __forceinline__ void tridec(int u, int &bi, int &bj) {
    int b = (int)(0.5f*(sqrtf(8.0f*(float)u + 1.0f) - 1.0f));
    while ((b+1)*(b+2)/2 <= u) ++b;
    while (b*(b+1)/2 > u) --b;
    bi = b; bj = u - b*(b+1)/2;
}

// Gram: Out = X^T X (= X^2 for symmetric X), lower-triangle + mirror
__global__ __launch_bounds__(512,1)
void gram_tri(const float* __restrict__ X, float* __restrict__ Out)
{
    __shared__ __align__(16) float LX[NM][PAD];
    const int t = threadIdx.x;
    const long long off = (long long)blockIdx.x << 14;
    for (int v = 0; v < 8; ++v) {
        int f = t + v*512;
        int row = f >> 5, c4 = (f & 31) << 2;
        *(float4*)&LX[row][c4] = ((const float4*)(X + off))[f];
    }
    __syncthreads();
    for (int u = t; u < 528; u += 512) {
        int bi, bj; tridec(u, bi, bj);
        const int r4 = bi << 2, c4 = bj << 2;
        float acc[4][4];
        #pragma unroll
        for (int i = 0; i < 4; ++i)
            #pragma unroll
            for (int j = 0; j < 4; ++j) acc[i][j] = 0.f;
        #pragma unroll 4
        for (int k = 0; k < NM; ++k) {
            float av[4], bv[4];
            *(float4*)av = *(const float4*)&LX[k][r4];
            *(float4*)bv = *(const float4*)&LX[k][c4];
            #pragma unroll
            for (int i = 0; i < 4; ++i)
                #pragma unroll
                for (int j = 0; j < 4; ++j) acc[i][j] = fmaf(av[i], bv[j], acc[i][j]);
        }
        #pragma unroll
        for (int i = 0; i < 4; ++i)
            *(float4*)&Out[off + (long long)(r4+i)*NM + c4] =
                make_float4(acc[i][0], acc[i][1], acc[i][2], acc[i][3]);
        if (bi != bj) {
            #pragma unroll
            for (int j = 0; j < 4; ++j)
                *(float4*)&Out[off + (long long)(c4+j)*NM + r4] =
                    make_float4(acc[0][j], acc[1][j], acc[2][j], acc[3][j]);
        }
    }
}

// ---------------------------------------------------------------- MFMA common
__device__ __forceinline__ f32x4 mfma16(bf16x8 a, bf16x8 b, f32x4 c) {
    return __builtin_amdgcn_mfma_f32_16x16x32_bf16(a, b, c, 0, 0, 0);
}

__device__ __forceinline__ void splitbf(float x, unsigned short &h, unsigned short &l) {
    __hip_bfloat16 bh = __float2bfloat16(x);
    float r = x - __bfloat162float(bh);
    __hip_bfloat16 bl = __float2bfloat16(r);
    h = *(unsigned short*)&bh;
    l = *(unsigned short*)&bl;
}

__device__ __forceinline__ float ldsM(const unsigned short* __restrict__ H,
                                      const unsigned short* __restrict__ L,
                                      int row, int col) {
    unsigned int uh = ((unsigned int)H[row*PB + col]) << 16;
    unsigned int ul = ((unsigned int)L[row*PB + col]) << 16;
    return __uint_as_float(uh) + __uint_as_float(ul);
}

__device__ __forceinline__ bf16x8 ldfrag(const unsigned short* __restrict__ a,
                                         int rb, int lane, int kc) {
    int row = rb*16 + (lane & 15);
    int col = kc*32 + ((lane >> 4) & 3)*8;
    return *(const bf16x8*)(a + row*PB + col);
}

// Exact symmetrization of a DIAGONAL 16x16 tile (C/D layout: col=lane&15,
// row=(lane>>4)*4+reg; transpose of (row rb+r, col) at lane'=4g+r+16(j>>2)).
__device__ __forceinline__ f32x4 symdiag(f32x4 a, int lane) {
    const int g = (lane >> 4) & 3, j = lane & 15;
    const int rp = j & 3;
    f32x4 out;
    #pragma unroll
    for (int r = 0; r < 4; ++r) {
        int lp = 4*g + r + ((j >> 2) << 4);
        float t0 = __shfl(a[0], lp, 64);
        float t1 = __shfl(a[1], lp, 64);
        float t2 = __shfl(a[2], lp, 64);
        float t3 = __shfl(a[3], lp, 64);
        float tv = (rp == 0) ? t0 : (rp == 1) ? t1 : (rp == 2) ? t2 : t3;
        out[r] = 0.5f*(a[r] + tv);
    }
    return out;
}

// write symmetric tile back to LDS as bf16 hi/lo splits (+ mirror)
__device__ __forceinline__ void st_split(unsigned short* __restrict__ H,
                                         unsigned short* __restrict__ L,
                                         int Tr, int Tc, int lane, f32x4 o) {
    int col = Tc*16 + (lane & 15);
    int rb  = Tr*16 + ((lane >> 4) & 3)*4;
    #pragma unroll
    for (int r = 0; r < 4; ++r) {
        unsigned short h, l;
        splitbf(o[r], h, l);
        H[(rb+r)*PB + col] = h;
        L[(rb+r)*PB + col] = l;
        if (Tr != Tc) { H[col*PB + rb + r] = h; L[col*PB + rb + r] = l; }
    }
}

__device__ __forceinline__ void stg_sym(float* __restrict__ out, long long off,
                                        int Tr, int Tc, int lane, f32x4 o) {
    int col = Tc*16 + (lane & 15);
    int rb  = Tr*16 + ((lane >> 4) & 3)*4;
    #pragma unroll
    for (int r = 0; r < 4; ++r)
        out[off + (long long)(rb+r)*NM + col] = o[r];
    if (Tr != Tc)
        *(f32x4*)&out[off + (long long)col*NM + rb] = o;
}

__device__ __forceinline__ f32x4 yepi(const unsigned short* __restrict__ Yh,
                                      const unsigned short* __restrict__ Yl,
                                      int Tr, int Tc, int lane, f32x4 a,
                                      float a15, float a05) {
    int col = Tc*16 + (lane & 15);
    int rb  = Tr*16 + ((lane >> 4) & 3)*4;
    f32x4 o;
    #pragma unroll
    for (int r = 0; r < 4; ++r)
        o[r] = a15*ldsM(Yh, Yl, rb+r, col) - a05*a[r];
    if (Tr == Tc) o = symdiag(o, lane);
    return o;
}

__device__ __forceinline__ f32x4 mepi(const unsigned short* __restrict__ Mh,
                                      const unsigned short* __restrict__ Ml,
                                      const unsigned short* __restrict__ Th,
                                      const unsigned short* __restrict__ Tl,
                                      int Tr, int Tc, int lane, f32x4 a, float q) {
    int col = Tc*16 + (lane & 15);
    int rb  = Tr*16 + ((lane >> 4) & 3)*4;
    f32x4 o;
    #pragma unroll
    for (int r = 0; r < 4; ++r)
        o[r] = q*(9.f*ldsM(Mh, Ml, rb+r, col) - 6.f*ldsM(Th, Tl, rb+r, col) + a[r]);
    if (Tr == Tc) o = symdiag(o, lane);
    return o;
}

__device__ __forceinline__ f32x4 pepi(const unsigned short* __restrict__ Ph,
                                      const unsigned short* __restrict__ Pl,
                                      int Tr, int Tc, int lane, f32x4 a,
                                      float s1, float s2, float dadd) {
    int col = Tc*16 + (lane & 15);
    int rb  = Tr*16 + ((lane >> 4) & 3)*4;
    f32x4 o;
    #pragma unroll
    for (int r = 0; r < 4; ++r)
        o[r] = s1*a[r] - s2*ldsM(Ph, Pl, rb+r, col) + ((rb+r) == col ? dadd : 0.f);
    if (Tr == Tc) o = symdiag(o, lane);
    return o;
}

// ---- 16-wave tile partition ----
template<int W>
struct TS16 {
    static constexpr int P  = W >> 2;
    static constexpr int Q  = W & 3;
    static constexpr int R0 = P;
    static constexpr int R1 = 7 - P;
    static constexpr int N  = (Q == 0) ? 3 : 2;
    static constexpr int g(int i)  { return 4*i + Q; }
    static constexpr int tr(int i) { return g(i) <= R0 ? R0 : R1; }
    static constexpr int tc(int i) { return g(i) <= R0 ? g(i) : g(i) - R0 - 1; }
};

template<int W>
__device__ __forceinline__ void tri16_gemm(const unsigned short* __restrict__ Ah,
                                           const unsigned short* __restrict__ Al,
                                           const unsigned short* __restrict__ Bh,
                                           const unsigned short* __restrict__ Bl,
                                           int lane, f32x4* acc) {
    using TS = TS16<W>;
    #pragma unroll
    for (int kc = 0; kc < 4; ++kc) {
        bf16x8 a0h = ldfrag(Ah, TS::R0, lane, kc), a0l = ldfrag(Al, TS::R0, lane, kc);
        bf16x8 a1h = ldfrag(Ah, TS::R1, lane, kc), a1l = ldfrag(Al, TS::R1, lane, kc);
        #pragma unroll
        for (int i = 0; i < TS::N; ++i) {
            const int r = TS::tr(i), c = TS::tc(i);
            bf16x8 bh = ldfrag(Bh, c, lane, kc), bl = ldfrag(Bl, c, lane, kc);
            bf16x8 ah = (r == TS::R0) ? a0h : a1h;
            bf16x8 al = (r == TS::R0) ? a0l : a1l;
            acc[i] = mfma16(ah, bh, acc[i]);
            acc[i] = mfma16(ah, bl, acc[i]);
            acc[i] = mfma16(al, bh, acc[i]);
        }
    }
}

// ---------------------------------------------------------------- fused NS
template<int W>
__device__ __forceinline__ void ns_fused_body16(
    unsigned short* Mh, unsigned short* Ml,
    unsigned short* Yh, unsigned short* Yl,
    float* outY, long long off, int lane, int niter)
{
    using TS = TS16<W>;
    constexpr int NT_ = TS::N;
    const f32x4 z = {0.f, 0.f, 0.f, 0.f};
    f32x4 acc[NT_], yv[NT_];

    for (int j = 0; j < niter; ++j) {
        const int last = (j == niter-1);
        const float cc = (j < niter-3) ? 1.5f : ((j == niter-3) ? 1.116f : 1.0f);
        const float dd = sqrtf(cc);
        const float a15 = 1.5f*dd, a05 = 0.5f*dd;

        #pragma unroll
        for (int i = 0; i < NT_; ++i) acc[i] = z;
        tri16_gemm<W>(Yh, Yl, Mh, Ml, lane, acc);
        #pragma unroll
        for (int i = 0; i < NT_; ++i)
            yv[i] = yepi(Yh, Yl, TS::tr(i), TS::tc(i), lane, acc[i], a15, a05);

        if (last) {
            #pragma unroll
            for (int i = 0; i < NT_; ++i)
                stg_sym(outY, off, TS::tr(i), TS::tc(i), lane, yv[i]);
            return;
        }
        __syncthreads();

        #pragma unroll
        for (int i = 0; i < NT_; ++i) acc[i] = z;
        tri16_gemm<W>(Mh, Ml, Mh, Ml, lane, acc);
        #pragma unroll
        for (int i = 0; i < NT_; ++i)
            st_split(Yh, Yl, TS::tr(i), TS::tc(i), lane, acc[i]);
        __syncthreads();

        #pragma unroll
        for (int i = 0; i < NT_; ++i) acc[i] = z;
        tri16_gemm<W>(Mh, Ml, Yh, Yl, lane, acc);
        const float q = 0.25f*cc;
        #pragma unroll
        for (int i = 0; i < NT_; ++i)
            acc[i] = mepi(Mh, Ml, Yh, Yl, TS::tr(i), TS::tc(i), lane, acc[i], q);
        __syncthreads();

        #pragma unroll
        for (int i = 0; i < NT_; ++i)
            st_split(Mh, Ml, TS::tr(i), TS::tc(i), lane, acc[i]);
        #pragma unroll
        for (int i = 0; i < NT_; ++i)
            st_split(Yh, Yl, TS::tr(i), TS::tc(i), lane, yv[i]);
        __syncthreads();
    }
}

__global__ __launch_bounds__(1024,1)
void ns_fused(const float* __restrict__ Mp, const float* __restrict__ Yp,
              float* __restrict__ outY, int niter)
{
    __shared__ __align__(16) unsigned short pool[4*NM*PB];
    unsigned short* Mh = pool;
    unsigned short* Ml = pool + NM*PB;
    unsigned short* Yh = pool + 2*NM*PB;
    unsigned short* Yl = pool + 3*NM*PB;

    const int t = threadIdx.x;
    const long long off = (long long)blockIdx.x << 14;
    for (int v = 0; v < 4; ++v) {
        int f = t + v*1024;
        int row = f >> 5, c4 = (f & 31) << 2;
        float4 x = ((const float4*)(Mp + off))[f];
        ushort4 h, l;
        splitbf(x.x, h.x, l.x); splitbf(x.y, h.y, l.y);
        splitbf(x.z, h.z, l.z); splitbf(x.w, h.w, l.w);
        *(ushort4*)&Mh[row*PB + c4] = h;
        *(ushort4*)&Ml[row*PB + c4] = l;
        x = ((const float4*)(Yp + off))[f];
        splitbf(x.x, h.x, l.x); splitbf(x.y, h.y, l.y);
        splitbf(x.z, h.z, l.z); splitbf(x.w, h.w, l.w);
        *(ushort4*)&Yh[row*PB + c4] = h;
        *(ushort4*)&Yl[row*PB + c4] = l;
    }
    __syncthreads();

    const int lane = t & 63;
    const int w = t >> 6;
    switch (w) {
        case 0:  ns_fused_body16<0>(Mh,Ml,Yh,Yl,outY,off,lane,niter); break;
        case 1:  ns_fused_body16<1>(Mh,Ml,Yh,Yl,outY,off,lane,niter); break;
        case 2:  ns_fused_body16<2>(Mh,Ml,Yh,Yl,outY,off,lane,niter); break;
        case 3:  ns_fused_body16<3>(Mh,Ml,Yh,Yl,outY,off,lane,niter); break;
        case 4:  ns_fused_body16<4>(Mh,Ml,Yh,Yl,outY,off,lane,niter); break;
        case 5:  ns_fused_body16<5>(Mh,Ml,Yh,Yl,outY,off,lane,niter); break;
        case 6:  ns_fused_body16<6>(Mh,Ml,Yh,Yl,outY,off,lane,niter); break;
        case 7:  ns_fused_body16<7>(Mh,Ml,Yh,Yl,outY,off,lane,niter); break;
        case 8:  ns_fused_body16<8>(Mh,Ml,Yh,Yl,outY,off,lane,niter); break;
        case 9:  ns_fused_body16<9>(Mh,Ml,Yh,Yl,outY,off,lane,niter); break;
        case 10: ns_fused_body16<10>(Mh,Ml,Yh,Yl,outY,off,lane,niter); break;
        case 11: ns_fused_body16<11>(Mh,Ml,Yh,Yl,outY,off,lane,niter); break;
        case 12: ns_fused_body16<12>(Mh,Ml,Yh,Yl,outY,off,lane,niter); break;
        case 13: ns_fused_body16<13>(Mh,Ml,Yh,Yl,outY,off,lane,niter); break;
        case 14: ns_fused_body16<14>(Mh,Ml,Yh,Yl,outY,off,lane,niter); break;
        default: ns_fused_body16<15>(Mh,Ml,Yh,Yl,outY,off,lane,niter); break;
    }
}

// ---------------------------------------------------------------- fused poly
struct PolyCoefs {
    float a, bd;
    float s1, s2;
    float c0,c1,c2,c3,c4,c5;
    float f1, f2, f3;
};

template<int W>
__device__ __forceinline__ void poly_fused_body16(
    const unsigned short* Xh, const unsigned short* Xl,
    unsigned short* Ph, unsigned short* Pl,
    float* Out, long long off, int lane, PolyCoefs pc, float lnsb)
{
    using TS = TS16<W>;
    constexpr int NT_ = TS::N;
    const f32x4 z = {0.f, 0.f, 0.f, 0.f};
    f32x4 acc[NT_];

    for (int step = 0; step < 6; ++step) {
        #pragma unroll
        for (int i = 0; i < NT_; ++i) acc[i] = z;
        tri16_gemm<W>(Xh, Xl, Ph, Pl, lane, acc);
        float s3v;
        switch (step) {
            case 0: s3v = pc.c0; break;  case 1: s3v = pc.c1; break;
            case 2: s3v = pc.c2; break;  case 3: s3v = pc.c3; break;
            case 4: s3v = pc.c4; break;  default: s3v = pc.c5; break;
        }
        #pragma unroll
        for (int i = 0; i < NT_; ++i)
            acc[i] = pepi(Ph, Pl, TS::tr(i), TS::tc(i), lane, acc[i], pc.s1, pc.s2, s3v);
        __syncthreads();
        #pragma unroll
        for (int i = 0; i < NT_; ++i)
            st_split(Ph, Pl, TS::tr(i), TS::tc(i), lane, acc[i]);
        __syncthreads();
    }
    #pragma unroll
    for (int i = 0; i < NT_; ++i) acc[i] = z;
    tri16_gemm<W>(Xh, Xl, Ph, Pl, lane, acc);
    const float dadd = pc.f3 + lnsb;
    #pragma unroll
    for (int i = 0; i < NT_; ++i) {
        f32x4 o = pepi(Ph, Pl, TS::tr(i), TS::tc(i), lane, acc[i], pc.f1, pc.f2, dadd);
        stg_sym(Out, off, TS::tr(i), TS::tc(i), lane, o);
    }
}

__global__ __launch_bounds__(1024,1)
void poly_fused(const float* __restrict__ Xp, float* __restrict__ Out,
                const float* __restrict__ lns, PolyCoefs pc)
{
    __shared__ __align__(16) unsigned short pool[4*NM*PB];
    unsigned short* Xh = pool;
    unsigned short* Xl = pool + NM*PB;
    unsigned short* Ph = pool + 2*NM*PB;
    unsigned short* Pl = pool + 3*NM*PB;

    const int t = threadIdx.x;
    const long long b = blockIdx.x;
    const long long off = b << 14;
    for (int v = 0; v < 4; ++v) {
        int f = t + v*1024;
        int row = f >> 5, c4 = (f & 31) << 2;
        float4 x = ((const float4*)(Xp + off))[f];
        float4 p;
        p.x = pc.a*x.x + ((c4+0)==row ? pc.bd : 0.f);
        p.y = pc.a*x.y + ((c4+1)==row ? pc.bd : 0.f);
        p.z = pc.a*x.z + ((c4+2)==row ? pc.bd : 0.f);
        p.w = pc.a*x.w + ((c4+3)==row ? pc.bd : 0.f);
        ushort4 h, l;
        splitbf(x.x, h.x, l.x); splitbf(x.y, h.y, l.y);
        splitbf(x.z, h.z, l.z); splitbf(x.w, h.w, l.w);
        *(ushort4*)&Xh[row*PB + c4] = h;
        *(ushort4*)&Xl[row*PB + c4] = l;
        splitbf(p.x, h.x, l.x); splitbf(p.y, h.y, l.y);
        splitbf(p.z, h.z, l.z); splitbf(p.w, h.w, l.w);
        *(ushort4*)&Ph[row*PB + c4] = h;
        *(ushort4*)&Pl[row*PB + c4] = l;
    }
    __syncthreads();

    const float lnsb = lns[b];
    const int lane = t & 63;
    const int w = t >> 6;
    switch (w) {
        case 0:  poly_fused_body16<0>(Xh,Xl,Ph,Pl,Out,off,lane,pc,lnsb); break;
        case 1:  poly_fused_body16<1>(Xh,Xl,Ph,Pl,Out,off,lane,pc,lnsb); break;
        case 2:  poly_fused_body16<2>(Xh,Xl,Ph,Pl,Out,off,lane,pc,lnsb); break;
        case 3:  poly_fused_body16<3>(Xh,Xl,Ph,Pl,Out,off,lane,pc,lnsb); break;
        case 4:  poly_fused_body16<4>(Xh,Xl,Ph,Pl,Out,off,lane,pc,lnsb); break;
        case 5:  poly_fused_body16<5>(Xh,Xl,Ph,Pl,Out,off,lane,pc,lnsb); break;
        case 6:  poly_fused_body16<6>(Xh,Xl,Ph,Pl,Out,off,lane,pc,lnsb); break;
        case 7:  poly_fused_body16<7>(Xh,Xl,Ph,Pl,Out,off,lane,pc,lnsb); break;
        case 8:  poly_fused_body16<8>(Xh,Xl,Ph,Pl,Out,off,lane,pc,lnsb); break;
        case 9:  poly_fused_body16<9>(Xh,Xl,Ph,Pl,Out,off,lane,pc,lnsb); break;
        case 10: poly_fused_body16<10>(Xh,Xl,Ph,Pl,Out,off,lane,pc,lnsb); break;
        case 11: poly_fused_body16<11>(Xh,Xl,Ph,Pl,Out,off,lane,pc,lnsb); break;
        case 12: poly_fused_body16<12>(Xh,Xl,Ph,Pl,Out,off,lane,pc,lnsb); break;
        case 13: poly_fused_body16<13>(Xh,Xl,Ph,Pl,Out,off,lane,pc,lnsb); break;
        case 14: poly_fused_body16<14>(Xh,Xl,Ph,Pl,Out,off,lane,pc,lnsb); break;
        default: poly_fused_body16<15>(Xh,Xl,Ph,Pl,Out,off,lane,pc,lnsb); break;
    }
}

// ============================================================================
// i8-MFMA exact 24-bit fixed-point NS (first 4 iterations)
// ============================================================================
__device__ __forceinline__ i32x4 mfma8(i32x4 a, i32x4 b, i32x4 c) {
    return __builtin_amdgcn_mfma_i32_16x16x64_i8(a, b, c, 0, 0, 0);
}

// exact 3-piece i8 split of round(x * 2^21): xi = h*2^16 + m*2^8 + l
__device__ __forceinline__ void spliti(float x, int &h, int &m, int &l) {
    int xi = __float2int_rn(x * 2097152.0f);
    l = (int)(signed char)(xi & 255);
    int r1 = (xi - l) >> 8;
    m = (int)(signed char)(r1 & 255);
    h = (r1 - m) >> 8;
}

__device__ __forceinline__ void pack4i(float4 x, unsigned &uh, unsigned &um, unsigned &ul) {
    float v[4] = {x.x, x.y, x.z, x.w};
    uh = um = ul = 0;
    #pragma unroll
    for (int i = 0; i < 4; ++i) {
        int h, m, l;
        spliti(v[i], h, m, l);
        uh |= ((unsigned)(h & 255)) << (8*i);
        um |= ((unsigned)(m & 255)) << (8*i);
        ul |= ((unsigned)(l & 255)) << (8*i);
    }
}

__device__ __forceinline__ float recLDS(const signed char* __restrict__ H,
                                        const signed char* __restrict__ Md,
                                        const signed char* __restrict__ L,
                                        int row, int col) {
    int v = ((int)H[row*PBI + col] << 16) + ((int)Md[row*PBI + col] << 8)
          + (int)L[row*PBI + col];
    return (float)v * 4.76837158203125e-7f;   // 2^-21
}

// recombine 4 weight-grouped i32 accumulators:
// x*y = g0*2^-10 + g1*2^-18 + g2*2^-26 + g3*2^-34  (ll term dropped, <=4.7e-7)
__device__ __forceinline__ f32x4 rec4(i32x4 g0, i32x4 g1, i32x4 g2, i32x4 g3) {
    f32x4 r;
    #pragma unroll
    for (int i = 0; i < 4; ++i)
        r[i] = (float)g0[i]*9.765625e-4f
             + (float)g1[i]*3.814697265625e-6f
             + (float)g2[i]*1.4901161193847656e-8f
             + (float)g3[i]*5.8207660913467407e-11f;
    return r;
}

__device__ __forceinline__ i32x4 ldfrag8(const signed char* __restrict__ p,
                                         int rb, int lane, int kc) {
    int row = rb*16 + (lane & 15);
    int col = kc*64 + ((lane >> 4) & 3)*16;
    return *(const i32x4*)(p + row*PBI + col);
}

__device__ __forceinline__ void st_spliti(signed char* __restrict__ H,
                                          signed char* __restrict__ Md,
                                          signed char* __restrict__ L,
                                          int Tr, int Tc, int lane, f32x4 o) {
    int col = Tc*16 + (lane & 15);
    int rb  = Tr*16 + ((lane >> 4) & 3)*4;
    #pragma unroll
    for (int r = 0; r < 4; ++r) {
        int h, m, l;
        spliti(o[r], h, m, l);
        H[(rb+r)*PBI + col] = (signed char)h;
        Md[(rb+r)*PBI + col] = (signed char)m;
        L[(rb+r)*PBI + col] = (signed char)l;
        if (Tr != Tc) {
            H[col*PBI + rb + r] = (signed char)h;
            Md[col*PBI + rb + r] = (signed char)m;
            L[col*PBI + rb + r] = (signed char)l;
        }
    }
}

// 8-wave tile partition (5/4 tiles per wave, union = 36 lower tiles)
template<int W>
struct TS8 {
    static constexpr int P  = W & 3;
    static constexpr int R0 = P;
    static constexpr int R1 = 7 - P;
    static constexpr int H  = W >> 2;
    static constexpr int N  = (10 - H) / 2;
    static constexpr int tr(int i) { int g = 2*i + H; return g <= R0 ? R0 : R1; }
    static constexpr int tc(int i) { int g = 2*i + H; return g <= R0 ? g : g - R0 - 1; }
};

template<int W>
__device__ __forceinline__ void tri8_gemm_i8(
    const signed char* __restrict__ Ah, const signed char* __restrict__ Am,
    const signed char* __restrict__ Al,
    const signed char* __restrict__ Bh, const signed char* __restrict__ Bm,
    const signed char* __restrict__ Bl,
    int lane, i32x4* g0, i32x4* g1, i32x4* g2, i32x4* g3)
{
    using TS = TS8<W>;
    #pragma unroll
    for (int kc = 0; kc < 2; ++kc) {
        i32x4 a0h = ldfrag8(Ah, TS::R0, lane, kc);
        i32x4 a0m = ldfrag8(Am, TS::R0, lane, kc);
        i32x4 a0l = ldfrag8(Al, TS::R0, lane, kc);
        i32x4 a1h = ldfrag8(Ah, TS::R1, lane, kc);
        i32x4 a1m = ldfrag8(Am, TS::R1, lane, kc);
        i32x4 a1l = ldfrag8(Al, TS::R1, lane, kc);
        #pragma unroll
        for (int i = 0; i < TS::N; ++i) {
            const int r = TS::tr(i), c = TS::tc(i);
            i32x4 bh = ldfrag8(Bh, c, lane, kc);
            i32x4 bm = ldfrag8(Bm, c, lane, kc);
            i32x4 bl = ldfrag8(Bl, c, lane, kc);
            i32x4 ah = (r == TS::R0) ? a0h : a1h;
            i32x4 am = (r == TS::R0) ? a0m : a1m;
            i32x4 al = (r == TS::R0) ? a0l : a1l;
            g0[i] = mfma8(ah, bh, g0[i]);
            g1[i] = mfma8(ah, bm, g1[i]);
            g1[i] = mfma8(am, bh, g1[i]);
            g2[i] = mfma8(ah, bl, g2[i]);
            g2[i] = mfma8(am, bm, g2[i]);
            g2[i] = mfma8(al, bh, g2[i]);
            g3[i] = mfma8(am, bl, g3[i]);
            g3[i] = mfma8(al, bm, g3[i]);
        }
    }
}

template<int W>
__device__ __forceinline__ void ns_i8_body(
    signed char* Mh, signed char* Mm, signed char* Ml,
    signed char* Yh, signed char* Ym, signed char* Yl,   // double as T planes
    float* outM, float* outY, long long off, int lane, int niter)
{
    using TS = TS8<W>;
    constexpr int NT_ = TS::N;
    const i32x4 zi = {0, 0, 0, 0};
    i32x4 g0[NT_], g1[NT_], g2[NT_], g3[NT_];
    f32x4 yv[NT_], mv[NT_];
    const float cc = 1.5f, dd = sqrtf(1.5f);
    const float a15 = 1.5f*dd, a05 = 0.5f*dd, q = 0.25f*cc;

    for (int j = 0; j < niter; ++j) {
        const int last = (j == niter-1);

        // ---- phase 1: Y' = a15*Y - a05*(Y*M) -> regs ----
        #pragma unroll
        for (int i = 0; i < NT_; ++i) { g0[i]=zi; g1[i]=zi; g2[i]=zi; g3[i]=zi; }
        tri8_gemm_i8<W>(Yh,Ym,Yl, Mh,Mm,Ml, lane, g0,g1,g2,g3);
        #pragma unroll
        for (int i = 0; i < NT_; ++i) {
            f32x4 a = rec4(g0[i], g1[i], g2[i], g3[i]);
            int Tr = TS::tr(i), Tc = TS::tc(i);
            int col = Tc*16 + (lane & 15);
            int rb  = Tr*16 + ((lane >> 4) & 3)*4;
            f32x4 o;
            #pragma unroll
            for (int r = 0; r < 4; ++r)
                o[r] = a15*recLDS(Yh, Ym, Yl, rb+r, col) - a05*a[r];
            if (Tr == Tc) o = symdiag(o, lane);
            yv[i] = o;
        }
        __syncthreads();   // all Y-plane reads done; T overlays

        // ---- phase 2: T = M*M (Gram; int-exact, diag tiles symmetric) ----
        #pragma unroll
        for (int i = 0; i < NT_; ++i) { g0[i]=zi; g1[i]=zi; g2[i]=zi; g3[i]=zi; }
        tri8_gemm_i8<W>(Mh,Mm,Ml, Mh,Mm,Ml, lane, g0,g1,g2,g3);
        #pragma unroll
        for (int i = 0; i < NT_; ++i) {
            f32x4 tv = rec4(g0[i], g1[i], g2[i], g3[i]);
            st_spliti(Yh, Ym, Yl, TS::tr(i), TS::tc(i), lane, tv);
        }
        __syncthreads();

        // ---- phase 3: M' = q*(9M - 6T + M*T) -> regs ----
        #pragma unroll
        for (int i = 0; i < NT_; ++i) { g0[i]=zi; g1[i]=zi; g2[i]=zi; g3[i]=zi; }
        tri8_gemm_i8<W>(Mh,Mm,Ml, Yh,Ym,Yl, lane, g0,g1,g2,g3);
        #pragma unroll
        for (int i = 0; i < NT_; ++i) {
            f32x4 a = rec4(g0[i], g1[i], g2[i], g3[i]);
            int Tr = TS::tr(i), Tc = TS::tc(i);
            int col = Tc*16 + (lane & 15);
            int rb  = Tr*16 + ((lane >> 4) & 3)*4;
            f32x4 o;
            #pragma unroll
            for (int r = 0; r < 4; ++r)
                o[r] = q*(9.f*recLDS(Mh, Mm, Ml, rb+r, col)
                        - 6.f*recLDS(Yh, Ym, Yl, rb+r, col) + a[r]);
            if (Tr == Tc) o = symdiag(o, lane);
            mv[i] = o;
        }
        __syncthreads();   // all M/T-plane reads done

        if (last) {
            #pragma unroll
            for (int i = 0; i < NT_; ++i)
                stg_sym(outY, off, TS::tr(i), TS::tc(i), lane, yv[i]);
            #pragma unroll
            for (int i = 0; i < NT_; ++i)
                stg_sym(outM, off, TS::tr(i), TS::tc(i), lane, mv[i]);
        } else {
            #pragma unroll
            for (int i = 0; i < NT_; ++i)
                st_spliti(Mh, Mm, Ml, TS::tr(i), TS::tc(i), lane, mv[i]);
            #pragma unroll
            for (int i = 0; i < NT_; ++i)
                st_spliti(Yh, Ym, Yl, TS::tr(i), TS::tc(i), lane, yv[i]);
            __syncthreads();
        }
    }
}

__global__ __launch_bounds__(512,1)
void ns_i8(const float* __restrict__ Mp, const float* __restrict__ Yp,
           float* __restrict__ outM, float* __restrict__ outY, int niter)
{
    __shared__ __align__(16) signed char pool8[6*NM*PBI];   // 110.6 KB
    signed char* Mh = pool8;
    signed char* Mm = pool8 + 1*NM*PBI;
    signed char* Ml = pool8 + 2*NM*PBI;
    signed char* Yh = pool8 + 3*NM*PBI;
    signed char* Ym = pool8 + 4*NM*PBI;
    signed char* Yl = pool8 + 5*NM*PBI;

    const int t = threadIdx.x;
    const long long off = (long long)blockIdx.x << 14;
    for (int v = 0; v < 8; ++v) {
        int f = t + v*512;
        int row = f >> 5, c4 = (f & 31) << 2;
        unsigned uh, um, ul;
        float4 x = ((const float4*)(Mp + off))[f];
        pack4i(x, uh, um, ul);
        *(unsigned*)&Mh[row*PBI + c4] = uh;
        *(unsigned*)&Mm[row*PBI + c4] = um;
        *(unsigned*)&Ml[row*PBI + c4] = ul;
        x = ((const float4*)(Yp + off))[f];
        pack4i(x, uh, um, ul);
        *(unsigned*)&Yh[row*PBI + c4] = uh;
        *(unsigned*)&Ym[row*PBI + c4] = um;
        *(unsigned*)&Yl[row*PBI + c4] = ul;
    }
    __syncthreads();

    const int lane = t & 63;
    const int w = t >> 6;
    switch (w) {
        case 0:  ns_i8_body<0>(Mh,Mm,Ml,Yh,Ym,Yl,outM,outY,off,lane,niter); break;
        case 1:  ns_i8_body<1>(Mh,Mm,Ml,Yh,Ym,Yl,outM,outY,off,lane,niter); break;
        case 2:  ns_i8_body<2>(Mh,Mm,Ml,Yh,Ym,Yl,outM,outY,off,lane,niter); break;
        case 3:  ns_i8_body<3>(Mh,Mm,Ml,Yh,Ym,Yl,outM,outY,off,lane,niter); break;
        case 4:  ns_i8_body<4>(Mh,Mm,Ml,Yh,Ym,Yl,outM,outY,off,lane,niter); break;
        case 5:  ns_i8_body<5>(Mh,Mm,Ml,Yh,Ym,Yl,outM,outY,off,lane,niter); break;
        case 6:  ns_i8_body<6>(Mh,Mm,Ml,Yh,Ym,Yl,outM,outY,off,lane,niter); break;
        default: ns_i8_body<7>(Mh,Mm,Ml,Yh,Ym,Yl,outM,outY,off,lane,niter); break;
    }
}

// ============================================================================
// Fallback (ws too small): round-1 parallel Jacobi
// ============================================================================
#define LDA  129
#define NT   512
#define MAX_SWEEPS 14

__global__ __launch_bounds__(NT, 1)
void logeig_jacobi(const float* __restrict__ in, float* __restrict__ out)
{
    __shared__ float A[NM][LDA];
    __shared__ float V[NM][LDA];
    __shared__ float rc[64], rs[64];
    __shared__ float logd[NM];
    __shared__ float roff[NT/64], rdia[NT/64];
    __shared__ int   s_done;

    const int t = threadIdx.x;
    const long long b = blockIdx.x;
    const float* __restrict__ Ain  = in  + (b << 14);
    float* __restrict__       Aout = out + (b << 14);

    for (int k = 0; k < (NM*NM)/NT; ++k) {
        int idx = t + k*NT;
        int i = idx >> 7, j = idx & 127;
        A[i][j] = Ain[idx];
        V[i][j] = (i == j) ? 1.0f : 0.0f;
    }
    __syncthreads();

    for (int sweep = 0; sweep < MAX_SWEEPS; ++sweep) {
        for (int r = 0; r < NM-1; ++r) {
            if (t < 64) {
                int m = t, p, q;
                if (m == 0) { p = NM-1; q = r; }
                else {
                    p = r + m;            if (p >= NM-1) p -= (NM-1);
                    q = r - m + (NM-1);   if (q >= NM-1) q -= (NM-1);
                }
                float app = A[p][p], aqq = A[q][q], apq = A[p][q];
                float c = 1.0f, s = 0.0f;
                if (fabsf(apq) > 1e-12f*(fabsf(app)+fabsf(aqq)) + 1e-32f) {
                    float tau = (aqq - app) * 0.5f / apq;
                    float tt  = 1.0f / (fabsf(tau) + sqrtf(fmaf(tau,tau,1.0f)));
                    tt = (tau < 0.0f) ? -tt : tt;
                    c = rsqrtf(fmaf(tt,tt,1.0f));
                    s = tt * c;
                }
                rc[m] = c; rs[m] = s;
            }
            __syncthreads();
            for (int k = 0; k < (2*64*NM)/NT; ++k) {
                int task = t + k*NT;
                int i   = task & 127;
                int m   = (task >> 7) & 63;
                int isV = task >> 13;
                int p, q;
                if (m == 0) { p = NM-1; q = r; }
                else {
                    p = r + m;            if (p >= NM-1) p -= (NM-1);
                    q = r - m + (NM-1);   if (q >= NM-1) q -= (NM-1);
                }
                float c = rc[m], s = rs[m];
                if (isV == 0) {
                    float x = A[i][p], y = A[i][q];
                    A[i][p] = c*x - s*y;
                    A[i][q] = s*x + c*y;
                } else {
                    float x = V[i][p], y = V[i][q];
                    V[i][p] = c*x - s*y;
                    V[i][q] = s*x + c*y;
                }
            }
            __syncthreads();
            for (int k = 0; k < (64*NM)/NT; ++k) {
                int task = t + k*NT;
                int j = task & 127;
                int m = task >> 7;
                int p, q;
                if (m == 0) { p = NM-1; q = r; }
                else {
                    p = r + m;            if (p >= NM-1) p -= (NM-1);
                    q = r - m + (NM-1);   if (q >= NM-1) q -= (NM-1);
                }
                float c = rc[m], s = rs[m];
                float x = A[p][j], y = A[q][j];
                A[p][j] = c*x - s*y;
                A[q][j] = s*x + c*y;
            }
            __syncthreads();
        }
        float off2 = 0.0f, dia2 = 0.0f;
        for (int k = 0; k < (NM*NM)/NT; ++k) {
            int idx = t + k*NT;
            int i = idx >> 7, j = idx & 127;
            float v = A[i][j];
            if (i == j) dia2 += v*v; else off2 += v*v;
        }
        #pragma unroll
        for (int o = 32; o > 0; o >>= 1) {
            off2 += __shfl_down(off2, o, 64);
            dia2 += __shfl_down(dia2, o, 64);
        }
        if ((t & 63) == 0) { roff[t >> 6] = off2; rdia[t >> 6] = dia2; }
        __syncthreads();
        if (t == 0) {
            float o2 = 0.0f, d2 = 0.0f;
            for (int w = 0; w < NT/64; ++w) { o2 += roff[w]; d2 += rdia[w]; }
            s_done = (o2 <= 1e-13f * d2) ? 1 : 0;
        }
        __syncthreads();
        if (s_done) break;
    }

    if (t < NM) logd[t] = logf(fmaxf(A[t][t], 1e-12f));
    __syncthreads();
    for (int kk = 0; kk < (NM*NM)/NT; ++kk) {
        int idx = t + kk*NT;
        int i = idx >> 7, k = idx & 127;
        A[i][k] = V[i][k] * logd[k];
    }
    __syncthreads();
    {
        int i  = t >> 2;
        int jb = t & 3;
        float acc[32];
        #pragma unroll
        for (int jj = 0; jj < 32; ++jj) acc[jj] = 0.0f;
        for (int kk = 0; kk < NM; ++kk) {
            int k = (kk + jb) & 127;
            float w = A[i][k];
            #pragma unroll
            for (int jj = 0; jj < 32; ++jj)
                acc[jj] = fmaf(w, V[jb*32 + jj][k], acc[jj]);
        }
        #pragma unroll
        for (int jj = 0; jj < 32; ++jj)
            Aout[i*NM + jb*32 + jj] = acc[jj];
    }
}

// ============================================================================
// Host
// ============================================================================
static void cheb_log_power(double lo, double up, int deg, double* p)
{
    const int NC = deg + 1;
    const int MN = 64;
    double mid = 0.5*(lo+up), hw = 0.5*(up-lo);
    double cc[32];
    for (int j = 0; j < NC; ++j) {
        double s = 0.0;
        for (int m = 0; m < MN; ++m) {
            double th = M_PI*(m+0.5)/MN;
            s += log(mid + hw*cos(th)) * cos(j*th);
        }
        cc[j] = 2.0*s/MN;
    }
    double Tp[32] = {0}, Tc[32] = {0}, Tn[32];
    for (int j = 0; j < NC; ++j) p[j] = 0.0;
    Tp[0] = 1.0;  p[0] += 0.5*cc[0];
    Tc[1] = 1.0;  p[1] += cc[1];
    for (int k = 2; k <= deg; ++k) {
        for (int j = 0; j < NC; ++j) Tn[j] = -Tp[j];
        for (int j = 1; j < NC; ++j) Tn[j] += 2.0*Tc[j-1];
        for (int j = 0; j < NC; ++j) { p[j] += cc[k]*Tn[j]; Tp[j] = Tc[j]; Tc[j] = Tn[j]; }
    }
}

extern "C" void kernel_launch(void* const* d_in, const int* in_sizes, int n_in,
                              void* d_out, int out_size, void* d_ws, size_t ws_size,
                              hipStream_t stream) {
    const float* in = (const float*)d_in[0];
    float* out = (float*)d_out;
    const int batch = in_sizes[0] >> 14;                 // 4096
    const size_t matBytes = (size_t)batch * NM * NM * 4; // 256 MB
    const size_t need = matBytes + (size_t)batch * 4;

    if (ws_size < need) {   // fallback
        logeig_jacobi<<<batch, NT, 0, stream>>>(in, out);
        return;
    }

    float* Mbuf = (float*)d_ws;
    float* lns  = (float*)((char*)d_ws + matBytes);

    // --- scaling: s0 = gersh(A); tighten via sqrt(gersh((A/s0)^2)) ---
    scale_kernel<<<batch, 256, 0, stream>>>(in, out, Mbuf, lns);      // out = X0
    gram_tri<<<batch, 512, 0, stream>>>(out, Mbuf);                   // Mbuf = X0^2
    rescale_kernel<<<batch, 256, 0, stream>>>(Mbuf, out, Mbuf, lns);  // out=Mbuf=X

    // --- L1 iters 0-3 (precision-critical): exact 24-bit i8-MFMA ---
    ns_i8<<<batch, 512, 0, stream>>>(Mbuf, out, Mbuf, out, 4);

    // --- fused MFMA NS segments (schedule {1.5 x(n-3), 1.116, 1, 1}) ---
    ns_fused<<<batch, 1024, 0, stream>>>(Mbuf, out, out, 8);  // L1 iters 4..11
    ns_fused<<<batch, 1024, 0, stream>>>(out,  out, out, 8);  // L2 (M0=Y0)
    ns_fused<<<batch, 1024, 0, stream>>>(out,  out, out, 6);  // L3 (M0=Y0)

    // --- fused Chebyshev-minimax log, deg 8 on [0.25, 1.002] ---
    const double lo = 0.25, up = 1.002;
    const double mid = 0.5*(lo+up), hw = 0.5*(up-lo);
    double p[9];
    cheb_log_power(lo, up, 8, p);

    PolyCoefs pc;
    pc.a  = (float)(p[8]/hw);
    pc.bd = (float)(p[7] - p[8]*mid/hw);
    pc.s1 = (float)(1.0/hw);
    pc.s2 = (float)(mid/hw);
    pc.c0 = (float)p[6]; pc.c1 = (float)p[5]; pc.c2 = (float)p[4];
    pc.c3 = (float)p[3]; pc.c4 = (float)p[2]; pc.c5 = (float)p[1];
    pc.f1 = (float)(8.0/hw);
    pc.f2 = (float)(8.0*mid/hw);
    pc.f3 = (float)(8.0*p[0]);

    poly_fused<<<batch, 1024, 0, stream>>>(out, out, lns, pc);
}

// Round 14
// 5930.497 us; speedup vs baseline: 1.2363x; 1.2363x over previous
//
#include <hip/hip_runtime.h>
#include <hip/hip_bf16.h>
#include <math.h>

#define NM   128
#define PAD  132   // f32 LDS pitch
#define PB   136   // u16 LDS pitch for MFMA bf16 splits
#define PBI  144   // i8 plane pitch (bytes), 16B-aligned rows

typedef __attribute__((ext_vector_type(8))) short bf16x8;
typedef __attribute__((ext_vector_type(4))) float f32x4;
typedef __attribute__((ext_vector_type(4))) int   i32x4;

// ============================================================================
// log(A) = ln(s) I + 8 * cheb_log( NS_sqrt^3( A/s ) ).
// Round-14: round-13's ns_i8 was SCRATCH-SPILL bound (TS8 needs ~156 VGPRs,
// compiler capped 128 -> 4.8GB HBM spill traffic/dispatch). Fix: 16-wave
// partition (<=3 tiles/wave, g-arrays 48 regs) + Y' packed to 24-bit planes
// right after phase 1 (peak ~105 regs). Arithmetic bit-identical.
// Invariants: every matrix written is EXACTLY symmetric (mirror-write +
// symdiag-on-full-output); passthroughs read LDS-resident data only.
// ============================================================================

// ---------------------------------------------------------------- f32 kernels
__global__ __launch_bounds__(256,1)
void scale_kernel(const float* __restrict__ A, float* __restrict__ outY,
                  float* __restrict__ outM, float* __restrict__ lns)
{
    __shared__ __align__(16) float L[NM][PAD];
    __shared__ float rs[NM];
    __shared__ float s_inv;
    const int t = threadIdx.x;
    const long long b = blockIdx.x;
    const long long off = b << 14;
    for (int v = 0; v < 16; ++v) {
        int f = t + v*256;
        int row = f >> 5, c4 = (f & 31) << 2;
        *(float4*)&L[row][c4] = ((const float4*)(A + off))[f];
    }
    __syncthreads();
    if (t < NM) {
        float s = 0.f;
        for (int j = 0; j < NM; ++j) s += fabsf(L[t][j]);
        rs[t] = s;
    }
    __syncthreads();
    if (t < 64) {
        float m = fmaxf(rs[t], rs[t+64]);
        #pragma unroll
        for (int o = 32; o > 0; o >>= 1) m = fmaxf(m, __shfl_down(m, o, 64));
        if (t == 0) { s_inv = 1.0f/m; lns[b] = logf(m); }
    }
    __syncthreads();
    const float inv = s_inv;
    for (int v = 0; v < 16; ++v) {
        int f = t + v*256;
        int row = f >> 5, c4 = (f & 31) << 2;
        float4 x = *(const float4*)&L[row][c4];
        x.x *= inv; x.y *= inv; x.z *= inv; x.w *= inv;
        ((float4*)(outY + off))[f] = x;
        ((float4*)(outM + off))[f] = x;
    }
}

__global__ __launch_bounds__(256,1)
void rescale_kernel(const float* __restrict__ Sq, float* __restrict__ X,
                    float* __restrict__ M, float* __restrict__ lns)
{
    __shared__ __align__(16) float L[NM][PAD];
    __shared__ float rs[NM];
    __shared__ float s_g;
    const int t = threadIdx.x;
    const long long b = blockIdx.x;
    const long long off = b << 14;
    for (int v = 0; v < 16; ++v) {
        int f = t + v*256;
        int row = f >> 5, c4 = (f & 31) << 2;
        *(float4*)&L[row][c4] = ((const float4*)(Sq + off))[f];
    }
    __syncthreads();
    if (t < NM) {
        float s = 0.f;
        for (int j = 0; j < NM; ++j) s += fabsf(L[t][j]);
        rs[t] = s;
    }
    __syncthreads();
    if (t < 64) {
        float m = fmaxf(rs[t], rs[t+64]);
        #pragma unroll
        for (int o = 32; o > 0; o >>= 1) m = fmaxf(m, __shfl_down(m, o, 64));
        if (t == 0) { s_g = 1.0f/sqrtf(m); lns[b] = lns[b] + 0.5f*logf(m); }
    }
    __syncthreads();
    const float g = s_g;
    for (int v = 0; v < 16; ++v) {
        int f = t + v*256;
        float4 x = ((const float4*)(X + off))[f];
        x.x *= g; x.y *= g; x.z *= g; x.w *= g;
        ((float4*)(X + off))[f] = x;
        ((float4*)(M + off))[f] = x;
    }
}

// triangular index decode: u -> (bi,bj), bj<=bi
__device__ __forceinline__ void tridec(int u, int &bi, int &bj) {
    int b = (int)(0.5f*(sqrtf(8.0f*(float)u + 1.0f) - 1.0f));
    while ((b+1)*(b+2)/2 <= u) ++b;
    while (b*(b+1)/2 > u) --b;
    bi = b; bj = u - b*(b+1)/2;
}

// Gram: Out = X^T X (= X^2 for symmetric X), lower-triangle + mirror
__global__ __launch_bounds__(512,1)
void gram_tri(const float* __restrict__ X, float* __restrict__ Out)
{
    __shared__ __align__(16) float LX[NM][PAD];
    const int t = threadIdx.x;
    const long long off = (long long)blockIdx.x << 14;
    for (int v = 0; v < 8; ++v) {
        int f = t + v*512;
        int row = f >> 5, c4 = (f & 31) << 2;
        *(float4*)&LX[row][c4] = ((const float4*)(X + off))[f];
    }
    __syncthreads();
    for (int u = t; u < 528; u += 512) {
        int bi, bj; tridec(u, bi, bj);
        const int r4 = bi << 2, c4 = bj << 2;
        float acc[4][4];
        #pragma unroll
        for (int i = 0; i < 4; ++i)
            #pragma unroll
            for (int j = 0; j < 4; ++j) acc[i][j] = 0.f;
        #pragma unroll 4
        for (int k = 0; k < NM; ++k) {
            float av[4], bv[4];
            *(float4*)av = *(const float4*)&LX[k][r4];
            *(float4*)bv = *(const float4*)&LX[k][c4];
            #pragma unroll
            for (int i = 0; i < 4; ++i)
                #pragma unroll
                for (int j = 0; j < 4; ++j) acc[i][j] = fmaf(av[i], bv[j], acc[i][j]);
        }
        #pragma unroll
        for (int i = 0; i < 4; ++i)
            *(float4*)&Out[off + (long long)(r4+i)*NM + c4] =
                make_float4(acc[i][0], acc[i][1], acc[i][2], acc[i][3]);
        if (bi != bj) {
            #pragma unroll
            for (int j = 0; j < 4; ++j)
                *(float4*)&Out[off + (long long)(c4+j)*NM + r4] =
                    make_float4(acc[0][j], acc[1][j], acc[2][j], acc[3][j]);
        }
    }
}

// ---------------------------------------------------------------- MFMA common
__device__ __forceinline__ f32x4 mfma16(bf16x8 a, bf16x8 b, f32x4 c) {
    return __builtin_amdgcn_mfma_f32_16x16x32_bf16(a, b, c, 0, 0, 0);
}

__device__ __forceinline__ void splitbf(float x, unsigned short &h, unsigned short &l) {
    __hip_bfloat16 bh = __float2bfloat16(x);
    float r = x - __bfloat162float(bh);
    __hip_bfloat16 bl = __float2bfloat16(r);
    h = *(unsigned short*)&bh;
    l = *(unsigned short*)&bl;
}

__device__ __forceinline__ float ldsM(const unsigned short* __restrict__ H,
                                      const unsigned short* __restrict__ L,
                                      int row, int col) {
    unsigned int uh = ((unsigned int)H[row*PB + col]) << 16;
    unsigned int ul = ((unsigned int)L[row*PB + col]) << 16;
    return __uint_as_float(uh) + __uint_as_float(ul);
}

__device__ __forceinline__ bf16x8 ldfrag(const unsigned short* __restrict__ a,
                                         int rb, int lane, int kc) {
    int row = rb*16 + (lane & 15);
    int col = kc*32 + ((lane >> 4) & 3)*8;
    return *(const bf16x8*)(a + row*PB + col);
}

// Exact symmetrization of a DIAGONAL 16x16 tile (C/D layout: col=lane&15,
// row=(lane>>4)*4+reg; transpose of (row rb+r, col) at lane'=4g+r+16(j>>2)).
__device__ __forceinline__ f32x4 symdiag(f32x4 a, int lane) {
    const int g = (lane >> 4) & 3, j = lane & 15;
    const int rp = j & 3;
    f32x4 out;
    #pragma unroll
    for (int r = 0; r < 4; ++r) {
        int lp = 4*g + r + ((j >> 2) << 4);
        float t0 = __shfl(a[0], lp, 64);
        float t1 = __shfl(a[1], lp, 64);
        float t2 = __shfl(a[2], lp, 64);
        float t3 = __shfl(a[3], lp, 64);
        float tv = (rp == 0) ? t0 : (rp == 1) ? t1 : (rp == 2) ? t2 : t3;
        out[r] = 0.5f*(a[r] + tv);
    }
    return out;
}

// write symmetric tile back to LDS as bf16 hi/lo splits (+ mirror)
__device__ __forceinline__ void st_split(unsigned short* __restrict__ H,
                                         unsigned short* __restrict__ L,
                                         int Tr, int Tc, int lane, f32x4 o) {
    int col = Tc*16 + (lane & 15);
    int rb  = Tr*16 + ((lane >> 4) & 3)*4;
    #pragma unroll
    for (int r = 0; r < 4; ++r) {
        unsigned short h, l;
        splitbf(o[r], h, l);
        H[(rb+r)*PB + col] = h;
        L[(rb+r)*PB + col] = l;
        if (Tr != Tc) { H[col*PB + rb + r] = h; L[col*PB + rb + r] = l; }
    }
}

__device__ __forceinline__ void stg_sym(float* __restrict__ out, long long off,
                                        int Tr, int Tc, int lane, f32x4 o) {
    int col = Tc*16 + (lane & 15);
    int rb  = Tr*16 + ((lane >> 4) & 3)*4;
    #pragma unroll
    for (int r = 0; r < 4; ++r)
        out[off + (long long)(rb+r)*NM + col] = o[r];
    if (Tr != Tc)
        *(f32x4*)&out[off + (long long)col*NM + rb] = o;
}

__device__ __forceinline__ f32x4 yepi(const unsigned short* __restrict__ Yh,
                                      const unsigned short* __restrict__ Yl,
                                      int Tr, int Tc, int lane, f32x4 a,
                                      float a15, float a05) {
    int col = Tc*16 + (lane & 15);
    int rb  = Tr*16 + ((lane >> 4) & 3)*4;
    f32x4 o;
    #pragma unroll
    for (int r = 0; r < 4; ++r)
        o[r] = a15*ldsM(Yh, Yl, rb+r, col) - a05*a[r];
    if (Tr == Tc) o = symdiag(o, lane);
    return o;
}

__device__ __forceinline__ f32x4 mepi(const unsigned short* __restrict__ Mh,
                                      const unsigned short* __restrict__ Ml,
                                      const unsigned short* __restrict__ Th,
                                      const unsigned short* __restrict__ Tl,
                                      int Tr, int Tc, int lane, f32x4 a, float q) {
    int col = Tc*16 + (lane & 15);
    int rb  = Tr*16 + ((lane >> 4) & 3)*4;
    f32x4 o;
    #pragma unroll
    for (int r = 0; r < 4; ++r)
        o[r] = q*(9.f*ldsM(Mh, Ml, rb+r, col) - 6.f*ldsM(Th, Tl, rb+r, col) + a[r]);
    if (Tr == Tc) o = symdiag(o, lane);
    return o;
}

__device__ __forceinline__ f32x4 pepi(const unsigned short* __restrict__ Ph,
                                      const unsigned short* __restrict__ Pl,
                                      int Tr, int Tc, int lane, f32x4 a,
                                      float s1, float s2, float dadd) {
    int col = Tc*16 + (lane & 15);
    int rb  = Tr*16 + ((lane >> 4) & 3)*4;
    f32x4 o;
    #pragma unroll
    for (int r = 0; r < 4; ++r)
        o[r] = s1*a[r] - s2*ldsM(Ph, Pl, rb+r, col) + ((rb+r) == col ? dadd : 0.f);
    if (Tr == Tc) o = symdiag(o, lane);
    return o;
}

// ---- 16-wave tile partition: P = W>>2 -> rows (P, 7-P) tiles g=0..8,
// quarter Q = W&3 takes g in {Q, Q+4, Q+8} (3 or 2 tiles).
template<int W>
struct TS16 {
    static constexpr int P  = W >> 2;
    static constexpr int Q  = W & 3;
    static constexpr int R0 = P;
    static constexpr int R1 = 7 - P;
    static constexpr int N  = (Q == 0) ? 3 : 2;
    static constexpr int g(int i)  { return 4*i + Q; }
    static constexpr int tr(int i) { return g(i) <= R0 ? R0 : R1; }
    static constexpr int tc(int i) { return g(i) <= R0 ? g(i) : g(i) - R0 - 1; }
};

template<int W>
__device__ __forceinline__ void tri16_gemm(const unsigned short* __restrict__ Ah,
                                           const unsigned short* __restrict__ Al,
                                           const unsigned short* __restrict__ Bh,
                                           const unsigned short* __restrict__ Bl,
                                           int lane, f32x4* acc) {
    using TS = TS16<W>;
    #pragma unroll
    for (int kc = 0; kc < 4; ++kc) {
        bf16x8 a0h = ldfrag(Ah, TS::R0, lane, kc), a0l = ldfrag(Al, TS::R0, lane, kc);
        bf16x8 a1h = ldfrag(Ah, TS::R1, lane, kc), a1l = ldfrag(Al, TS::R1, lane, kc);
        #pragma unroll
        for (int i = 0; i < TS::N; ++i) {
            const int r = TS::tr(i), c = TS::tc(i);
            bf16x8 bh = ldfrag(Bh, c, lane, kc), bl = ldfrag(Bl, c, lane, kc);
            bf16x8 ah = (r == TS::R0) ? a0h : a1h;
            bf16x8 al = (r == TS::R0) ? a0l : a1l;
            acc[i] = mfma16(ah, bh, acc[i]);
            acc[i] = mfma16(ah, bl, acc[i]);
            acc[i] = mfma16(al, bh, acc[i]);
        }
    }
}

// ---------------------------------------------------------------- fused NS
template<int W>
__device__ __forceinline__ void ns_fused_body16(
    unsigned short* Mh, unsigned short* Ml,
    unsigned short* Yh, unsigned short* Yl,
    float* outY, long long off, int lane, int niter)
{
    using TS = TS16<W>;
    constexpr int NT_ = TS::N;
    const f32x4 z = {0.f, 0.f, 0.f, 0.f};
    f32x4 acc[NT_], yv[NT_];

    for (int j = 0; j < niter; ++j) {
        const int last = (j == niter-1);
        const float cc = (j < niter-3) ? 1.5f : ((j == niter-3) ? 1.116f : 1.0f);
        const float dd = sqrtf(cc);
        const float a15 = 1.5f*dd, a05 = 0.5f*dd;

        #pragma unroll
        for (int i = 0; i < NT_; ++i) acc[i] = z;
        tri16_gemm<W>(Yh, Yl, Mh, Ml, lane, acc);
        #pragma unroll
        for (int i = 0; i < NT_; ++i)
            yv[i] = yepi(Yh, Yl, TS::tr(i), TS::tc(i), lane, acc[i], a15, a05);

        if (last) {
            #pragma unroll
            for (int i = 0; i < NT_; ++i)
                stg_sym(outY, off, TS::tr(i), TS::tc(i), lane, yv[i]);
            return;
        }
        __syncthreads();

        #pragma unroll
        for (int i = 0; i < NT_; ++i) acc[i] = z;
        tri16_gemm<W>(Mh, Ml, Mh, Ml, lane, acc);
        #pragma unroll
        for (int i = 0; i < NT_; ++i)
            st_split(Yh, Yl, TS::tr(i), TS::tc(i), lane, acc[i]);
        __syncthreads();

        #pragma unroll
        for (int i = 0; i < NT_; ++i) acc[i] = z;
        tri16_gemm<W>(Mh, Ml, Yh, Yl, lane, acc);
        const float q = 0.25f*cc;
        #pragma unroll
        for (int i = 0; i < NT_; ++i)
            acc[i] = mepi(Mh, Ml, Yh, Yl, TS::tr(i), TS::tc(i), lane, acc[i], q);
        __syncthreads();

        #pragma unroll
        for (int i = 0; i < NT_; ++i)
            st_split(Mh, Ml, TS::tr(i), TS::tc(i), lane, acc[i]);
        #pragma unroll
        for (int i = 0; i < NT_; ++i)
            st_split(Yh, Yl, TS::tr(i), TS::tc(i), lane, yv[i]);
        __syncthreads();
    }
}

__global__ __launch_bounds__(1024,1)
void ns_fused(const float* __restrict__ Mp, const float* __restrict__ Yp,
              float* __restrict__ outY, int niter)
{
    __shared__ __align__(16) unsigned short pool[4*NM*PB];
    unsigned short* Mh = pool;
    unsigned short* Ml = pool + NM*PB;
    unsigned short* Yh = pool + 2*NM*PB;
    unsigned short* Yl = pool + 3*NM*PB;

    const int t = threadIdx.x;
    const long long off = (long long)blockIdx.x << 14;
    for (int v = 0; v < 4; ++v) {
        int f = t + v*1024;
        int row = f >> 5, c4 = (f & 31) << 2;
        float4 x = ((const float4*)(Mp + off))[f];
        ushort4 h, l;
        splitbf(x.x, h.x, l.x); splitbf(x.y, h.y, l.y);
        splitbf(x.z, h.z, l.z); splitbf(x.w, h.w, l.w);
        *(ushort4*)&Mh[row*PB + c4] = h;
        *(ushort4*)&Ml[row*PB + c4] = l;
        x = ((const float4*)(Yp + off))[f];
        splitbf(x.x, h.x, l.x); splitbf(x.y, h.y, l.y);
        splitbf(x.z, h.z, l.z); splitbf(x.w, h.w, l.w);
        *(ushort4*)&Yh[row*PB + c4] = h;
        *(ushort4*)&Yl[row*PB + c4] = l;
    }
    __syncthreads();

    const int lane = t & 63;
    const int w = t >> 6;
    switch (w) {
        case 0:  ns_fused_body16<0>(Mh,Ml,Yh,Yl,outY,off,lane,niter); break;
        case 1:  ns_fused_body16<1>(Mh,Ml,Yh,Yl,outY,off,lane,niter); break;
        case 2:  ns_fused_body16<2>(Mh,Ml,Yh,Yl,outY,off,lane,niter); break;
        case 3:  ns_fused_body16<3>(Mh,Ml,Yh,Yl,outY,off,lane,niter); break;
        case 4:  ns_fused_body16<4>(Mh,Ml,Yh,Yl,outY,off,lane,niter); break;
        case 5:  ns_fused_body16<5>(Mh,Ml,Yh,Yl,outY,off,lane,niter); break;
        case 6:  ns_fused_body16<6>(Mh,Ml,Yh,Yl,outY,off,lane,niter); break;
        case 7:  ns_fused_body16<7>(Mh,Ml,Yh,Yl,outY,off,lane,niter); break;
        case 8:  ns_fused_body16<8>(Mh,Ml,Yh,Yl,outY,off,lane,niter); break;
        case 9:  ns_fused_body16<9>(Mh,Ml,Yh,Yl,outY,off,lane,niter); break;
        case 10: ns_fused_body16<10>(Mh,Ml,Yh,Yl,outY,off,lane,niter); break;
        case 11: ns_fused_body16<11>(Mh,Ml,Yh,Yl,outY,off,lane,niter); break;
        case 12: ns_fused_body16<12>(Mh,Ml,Yh,Yl,outY,off,lane,niter); break;
        case 13: ns_fused_body16<13>(Mh,Ml,Yh,Yl,outY,off,lane,niter); break;
        case 14: ns_fused_body16<14>(Mh,Ml,Yh,Yl,outY,off,lane,niter); break;
        default: ns_fused_body16<15>(Mh,Ml,Yh,Yl,outY,off,lane,niter); break;
    }
}

// ---------------------------------------------------------------- fused poly
struct PolyCoefs {
    float a, bd;
    float s1, s2;
    float c0,c1,c2,c3,c4,c5;
    float f1, f2, f3;
};

template<int W>
__device__ __forceinline__ void poly_fused_body16(
    const unsigned short* Xh, const unsigned short* Xl,
    unsigned short* Ph, unsigned short* Pl,
    float* Out, long long off, int lane, PolyCoefs pc, float lnsb)
{
    using TS = TS16<W>;
    constexpr int NT_ = TS::N;
    const f32x4 z = {0.f, 0.f, 0.f, 0.f};
    f32x4 acc[NT_];

    for (int step = 0; step < 6; ++step) {
        #pragma unroll
        for (int i = 0; i < NT_; ++i) acc[i] = z;
        tri16_gemm<W>(Xh, Xl, Ph, Pl, lane, acc);
        float s3v;
        switch (step) {
            case 0: s3v = pc.c0; break;  case 1: s3v = pc.c1; break;
            case 2: s3v = pc.c2; break;  case 3: s3v = pc.c3; break;
            case 4: s3v = pc.c4; break;  default: s3v = pc.c5; break;
        }
        #pragma unroll
        for (int i = 0; i < NT_; ++i)
            acc[i] = pepi(Ph, Pl, TS::tr(i), TS::tc(i), lane, acc[i], pc.s1, pc.s2, s3v);
        __syncthreads();
        #pragma unroll
        for (int i = 0; i < NT_; ++i)
            st_split(Ph, Pl, TS::tr(i), TS::tc(i), lane, acc[i]);
        __syncthreads();
    }
    #pragma unroll
    for (int i = 0; i < NT_; ++i) acc[i] = z;
    tri16_gemm<W>(Xh, Xl, Ph, Pl, lane, acc);
    const float dadd = pc.f3 + lnsb;
    #pragma unroll
    for (int i = 0; i < NT_; ++i) {
        f32x4 o = pepi(Ph, Pl, TS::tr(i), TS::tc(i), lane, acc[i], pc.f1, pc.f2, dadd);
        stg_sym(Out, off, TS::tr(i), TS::tc(i), lane, o);
    }
}

__global__ __launch_bounds__(1024,1)
void poly_fused(const float* __restrict__ Xp, float* __restrict__ Out,
                const float* __restrict__ lns, PolyCoefs pc)
{
    __shared__ __align__(16) unsigned short pool[4*NM*PB];
    unsigned short* Xh = pool;
    unsigned short* Xl = pool + NM*PB;
    unsigned short* Ph = pool + 2*NM*PB;
    unsigned short* Pl = pool + 3*NM*PB;

    const int t = threadIdx.x;
    const long long b = blockIdx.x;
    const long long off = b << 14;
    for (int v = 0; v < 4; ++v) {
        int f = t + v*1024;
        int row = f >> 5, c4 = (f & 31) << 2;
        float4 x = ((const float4*)(Xp + off))[f];
        float4 p;
        p.x = pc.a*x.x + ((c4+0)==row ? pc.bd : 0.f);
        p.y = pc.a*x.y + ((c4+1)==row ? pc.bd : 0.f);
        p.z = pc.a*x.z + ((c4+2)==row ? pc.bd : 0.f);
        p.w = pc.a*x.w + ((c4+3)==row ? pc.bd : 0.f);
        ushort4 h, l;
        splitbf(x.x, h.x, l.x); splitbf(x.y, h.y, l.y);
        splitbf(x.z, h.z, l.z); splitbf(x.w, h.w, l.w);
        *(ushort4*)&Xh[row*PB + c4] = h;
        *(ushort4*)&Xl[row*PB + c4] = l;
        splitbf(p.x, h.x, l.x); splitbf(p.y, h.y, l.y);
        splitbf(p.z, h.z, l.z); splitbf(p.w, h.w, l.w);
        *(ushort4*)&Ph[row*PB + c4] = h;
        *(ushort4*)&Pl[row*PB + c4] = l;
    }
    __syncthreads();

    const float lnsb = lns[b];
    const int lane = t & 63;
    const int w = t >> 6;
    switch (w) {
        case 0:  poly_fused_body16<0>(Xh,Xl,Ph,Pl,Out,off,lane,pc,lnsb); break;
        case 1:  poly_fused_body16<1>(Xh,Xl,Ph,Pl,Out,off,lane,pc,lnsb); break;
        case 2:  poly_fused_body16<2>(Xh,Xl,Ph,Pl,Out,off,lane,pc,lnsb); break;
        case 3:  poly_fused_body16<3>(Xh,Xl,Ph,Pl,Out,off,lane,pc,lnsb); break;
        case 4:  poly_fused_body16<4>(Xh,Xl,Ph,Pl,Out,off,lane,pc,lnsb); break;
        case 5:  poly_fused_body16<5>(Xh,Xl,Ph,Pl,Out,off,lane,pc,lnsb); break;
        case 6:  poly_fused_body16<6>(Xh,Xl,Ph,Pl,Out,off,lane,pc,lnsb); break;
        case 7:  poly_fused_body16<7>(Xh,Xl,Ph,Pl,Out,off,lane,pc,lnsb); break;
        case 8:  poly_fused_body16<8>(Xh,Xl,Ph,Pl,Out,off,lane,pc,lnsb); break;
        case 9:  poly_fused_body16<9>(Xh,Xl,Ph,Pl,Out,off,lane,pc,lnsb); break;
        case 10: poly_fused_body16<10>(Xh,Xl,Ph,Pl,Out,off,lane,pc,lnsb); break;
        case 11: poly_fused_body16<11>(Xh,Xl,Ph,Pl,Out,off,lane,pc,lnsb); break;
        case 12: poly_fused_body16<12>(Xh,Xl,Ph,Pl,Out,off,lane,pc,lnsb); break;
        case 13: poly_fused_body16<13>(Xh,Xl,Ph,Pl,Out,off,lane,pc,lnsb); break;
        case 14: poly_fused_body16<14>(Xh,Xl,Ph,Pl,Out,off,lane,pc,lnsb); break;
        default: poly_fused_body16<15>(Xh,Xl,Ph,Pl,Out,off,lane,pc,lnsb); break;
    }
}

// ============================================================================
// i8-MFMA exact 24-bit fixed-point NS (first 4 iterations) — 16-wave version
// ============================================================================
__device__ __forceinline__ i32x4 mfma8(i32x4 a, i32x4 b, i32x4 c) {
    return __builtin_amdgcn_mfma_i32_16x16x64_i8(a, b, c, 0, 0, 0);
}

// exact 3-piece i8 split of round(x * 2^21): xi = h*2^16 + m*2^8 + l
__device__ __forceinline__ void spliti(float x, int &h, int &m, int &l) {
    int xi = __float2int_rn(x * 2097152.0f);
    l = (int)(signed char)(xi & 255);
    int r1 = (xi - l) >> 8;
    m = (int)(signed char)(r1 & 255);
    h = (r1 - m) >> 8;
}

__device__ __forceinline__ void pack4i(float4 x, unsigned &uh, unsigned &um, unsigned &ul) {
    float v[4] = {x.x, x.y, x.z, x.w};
    uh = um = ul = 0;
    #pragma unroll
    for (int i = 0; i < 4; ++i) {
        int h, m, l;
        spliti(v[i], h, m, l);
        uh |= ((unsigned)(h & 255)) << (8*i);
        um |= ((unsigned)(m & 255)) << (8*i);
        ul |= ((unsigned)(l & 255)) << (8*i);
    }
}

__device__ __forceinline__ float recLDS(const signed char* __restrict__ H,
                                        const signed char* __restrict__ Md,
                                        const signed char* __restrict__ L,
                                        int row, int col) {
    int v = ((int)H[row*PBI + col] << 16) + ((int)Md[row*PBI + col] << 8)
          + (int)L[row*PBI + col];
    return (float)v * 4.76837158203125e-7f;   // 2^-21
}

// recombine 4 weight-grouped i32 accumulators:
// x*y = g0*2^-10 + g1*2^-18 + g2*2^-26 + g3*2^-34  (ll term dropped, <=4.7e-7)
__device__ __forceinline__ f32x4 rec4(i32x4 g0, i32x4 g1, i32x4 g2, i32x4 g3) {
    f32x4 r;
    #pragma unroll
    for (int i = 0; i < 4; ++i)
        r[i] = (float)g0[i]*9.765625e-4f
             + (float)g1[i]*3.814697265625e-6f
             + (float)g2[i]*1.4901161193847656e-8f
             + (float)g3[i]*5.8207660913467407e-11f;
    return r;
}

__device__ __forceinline__ i32x4 ldfrag8(const signed char* __restrict__ p,
                                         int rb, int lane, int kc) {
    int row = rb*16 + (lane & 15);
    int col = kc*64 + ((lane >> 4) & 3)*16;
    return *(const i32x4*)(p + row*PBI + col);
}

// write packed 24-bit tile (bytes) to LDS planes (+ mirror)
__device__ __forceinline__ void st_packed(signed char* __restrict__ H,
                                          signed char* __restrict__ Md,
                                          signed char* __restrict__ L,
                                          int Tr, int Tc, int lane,
                                          unsigned yh, unsigned ym, unsigned yl) {
    int col = Tc*16 + (lane & 15);
    int rb  = Tr*16 + ((lane >> 4) & 3)*4;
    #pragma unroll
    for (int r = 0; r < 4; ++r) {
        signed char h = (signed char)((yh >> (8*r)) & 255);
        signed char m = (signed char)((ym >> (8*r)) & 255);
        signed char l = (signed char)((yl >> (8*r)) & 255);
        H[(rb+r)*PBI + col] = h;
        Md[(rb+r)*PBI + col] = m;
        L[(rb+r)*PBI + col] = l;
        if (Tr != Tc) {
            H[col*PBI + rb + r] = h;
            Md[col*PBI + rb + r] = m;
            L[col*PBI + rb + r] = l;
        }
    }
}

__device__ __forceinline__ void st_spliti(signed char* __restrict__ H,
                                          signed char* __restrict__ Md,
                                          signed char* __restrict__ L,
                                          int Tr, int Tc, int lane, f32x4 o) {
    int col = Tc*16 + (lane & 15);
    int rb  = Tr*16 + ((lane >> 4) & 3)*4;
    #pragma unroll
    for (int r = 0; r < 4; ++r) {
        int h, m, l;
        spliti(o[r], h, m, l);
        H[(rb+r)*PBI + col] = (signed char)h;
        Md[(rb+r)*PBI + col] = (signed char)m;
        L[(rb+r)*PBI + col] = (signed char)l;
        if (Tr != Tc) {
            H[col*PBI + rb + r] = (signed char)h;
            Md[col*PBI + rb + r] = (signed char)m;
            L[col*PBI + rb + r] = (signed char)l;
        }
    }
}

template<int W>
__device__ __forceinline__ void tri16_gemm_i8(
    const signed char* __restrict__ Ah, const signed char* __restrict__ Am,
    const signed char* __restrict__ Al,
    const signed char* __restrict__ Bh, const signed char* __restrict__ Bm,
    const signed char* __restrict__ Bl,
    int lane, i32x4* g0, i32x4* g1, i32x4* g2, i32x4* g3)
{
    using TS = TS16<W>;
    #pragma unroll
    for (int kc = 0; kc < 2; ++kc) {
        i32x4 a0h = ldfrag8(Ah, TS::R0, lane, kc);
        i32x4 a0m = ldfrag8(Am, TS::R0, lane, kc);
        i32x4 a0l = ldfrag8(Al, TS::R0, lane, kc);
        i32x4 a1h = ldfrag8(Ah, TS::R1, lane, kc);
        i32x4 a1m = ldfrag8(Am, TS::R1, lane, kc);
        i32x4 a1l = ldfrag8(Al, TS::R1, lane, kc);
        #pragma unroll
        for (int i = 0; i < TS::N; ++i) {
            const int r = TS::tr(i), c = TS::tc(i);
            i32x4 bh = ldfrag8(Bh, c, lane, kc);
            i32x4 bm = ldfrag8(Bm, c, lane, kc);
            i32x4 bl = ldfrag8(Bl, c, lane, kc);
            i32x4 ah = (r == TS::R0) ? a0h : a1h;
            i32x4 am = (r == TS::R0) ? a0m : a1m;
            i32x4 al = (r == TS::R0) ? a0l : a1l;
            g0[i] = mfma8(ah, bh, g0[i]);
            g1[i] = mfma8(ah, bm, g1[i]);
            g1[i] = mfma8(am, bh, g1[i]);
            g2[i] = mfma8(ah, bl, g2[i]);
            g2[i] = mfma8(am, bm, g2[i]);
            g2[i] = mfma8(al, bh, g2[i]);
            g3[i] = mfma8(am, bl, g3[i]);
            g3[i] = mfma8(al, bm, g3[i]);
        }
    }
}

template<int W>
__device__ __forceinline__ void ns_i8_body16(
    signed char* Mh, signed char* Mm, signed char* Ml,
    signed char* Yh, signed char* Ym, signed char* Yl,   // double as T planes
    float* outM, float* outY, long long off, int lane, int niter)
{
    using TS = TS16<W>;
    constexpr int NT_ = TS::N;
    const i32x4 zi = {0, 0, 0, 0};
    i32x4 g0[NT_], g1[NT_], g2[NT_], g3[NT_];
    unsigned yph[NT_], ypm[NT_], ypl[NT_];   // Y' packed 24-bit (saves regs)
    const float cc = 1.5f, dd = sqrtf(1.5f);
    const float a15 = 1.5f*dd, a05 = 0.5f*dd, q = 0.25f*cc;

    for (int j = 0; j < niter; ++j) {
        const int last = (j == niter-1);

        // ---- phase 1: Y' = a15*Y - a05*(Y*M) ----
        #pragma unroll
        for (int i = 0; i < NT_; ++i) { g0[i]=zi; g1[i]=zi; g2[i]=zi; g3[i]=zi; }
        tri16_gemm_i8<W>(Yh,Ym,Yl, Mh,Mm,Ml, lane, g0,g1,g2,g3);
        #pragma unroll
        for (int i = 0; i < NT_; ++i) {
            f32x4 a = rec4(g0[i], g1[i], g2[i], g3[i]);
            int Tr = TS::tr(i), Tc = TS::tc(i);
            int col = Tc*16 + (lane & 15);
            int rb  = Tr*16 + ((lane >> 4) & 3)*4;
            f32x4 o;
            #pragma unroll
            for (int r = 0; r < 4; ++r)
                o[r] = a15*recLDS(Yh, Ym, Yl, rb+r, col) - a05*a[r];
            if (Tr == Tc) o = symdiag(o, lane);
            if (last) {
                stg_sym(outY, off, Tr, Tc, lane, o);
            } else {
                float4 of = make_float4(o[0], o[1], o[2], o[3]);
                pack4i(of, yph[i], ypm[i], ypl[i]);
            }
        }
        __syncthreads();   // all Y-plane reads done; T overlays

        // ---- phase 2: T = M*M (Gram; int-exact, diag tiles symmetric) ----
        #pragma unroll
        for (int i = 0; i < NT_; ++i) { g0[i]=zi; g1[i]=zi; g2[i]=zi; g3[i]=zi; }
        tri16_gemm_i8<W>(Mh,Mm,Ml, Mh,Mm,Ml, lane, g0,g1,g2,g3);
        #pragma unroll
        for (int i = 0; i < NT_; ++i) {
            f32x4 tv = rec4(g0[i], g1[i], g2[i], g3[i]);
            st_spliti(Yh, Ym, Yl, TS::tr(i), TS::tc(i), lane, tv);
        }
        __syncthreads();

        // ---- phase 3: M' = q*(9M - 6T + M*T) ----
        #pragma unroll
        for (int i = 0; i < NT_; ++i) { g0[i]=zi; g1[i]=zi; g2[i]=zi; g3[i]=zi; }
        tri16_gemm_i8<W>(Mh,Mm,Ml, Yh,Ym,Yl, lane, g0,g1,g2,g3);
        if (last) {
            #pragma unroll
            for (int i = 0; i < NT_; ++i) {
                f32x4 a = rec4(g0[i], g1[i], g2[i], g3[i]);
                int Tr = TS::tr(i), Tc = TS::tc(i);
                int col = Tc*16 + (lane & 15);
                int rb  = Tr*16 + ((lane >> 4) & 3)*4;
                f32x4 o;
                #pragma unroll
                for (int r = 0; r < 4; ++r)
                    o[r] = q*(9.f*recLDS(Mh, Mm, Ml, rb+r, col)
                            - 6.f*recLDS(Yh, Ym, Yl, rb+r, col) + a[r]);
                if (Tr == Tc) o = symdiag(o, lane);
                stg_sym(outM, off, Tr, Tc, lane, o);
            }
            return;
        }
        {
            f32x4 mv[NT_];
            #pragma unroll
            for (int i = 0; i < NT_; ++i) {
                f32x4 a = rec4(g0[i], g1[i], g2[i], g3[i]);
                int Tr = TS::tr(i), Tc = TS::tc(i);
                int col = Tc*16 + (lane & 15);
                int rb  = Tr*16 + ((lane >> 4) & 3)*4;
                f32x4 o;
                #pragma unroll
                for (int r = 0; r < 4; ++r)
                    o[r] = q*(9.f*recLDS(Mh, Mm, Ml, rb+r, col)
                            - 6.f*recLDS(Yh, Ym, Yl, rb+r, col) + a[r]);
                if (Tr == Tc) o = symdiag(o, lane);
                mv[i] = o;
            }
            __syncthreads();   // all M/T-plane reads done
            #pragma unroll
            for (int i = 0; i < NT_; ++i)
                st_spliti(Mh, Mm, Ml, TS::tr(i), TS::tc(i), lane, mv[i]);
            #pragma unroll
            for (int i = 0; i < NT_; ++i)
                st_packed(Yh, Ym, Yl, TS::tr(i), TS::tc(i), lane,
                          yph[i], ypm[i], ypl[i]);
            __syncthreads();
        }
    }
}

__global__ __launch_bounds__(1024,1)
void ns_i8(const float* __restrict__ Mp, const float* __restrict__ Yp,
           float* __restrict__ outM, float* __restrict__ outY, int niter)
{
    __shared__ __align__(16) signed char pool8[6*NM*PBI];   // 110.6 KB
    signed char* Mh = pool8;
    signed char* Mm = pool8 + 1*NM*PBI;
    signed char* Ml = pool8 + 2*NM*PBI;
    signed char* Yh = pool8 + 3*NM*PBI;
    signed char* Ym = pool8 + 4*NM*PBI;
    signed char* Yl = pool8 + 5*NM*PBI;

    const int t = threadIdx.x;
    const long long off = (long long)blockIdx.x << 14;
    for (int v = 0; v < 4; ++v) {
        int f = t + v*1024;
        int row = f >> 5, c4 = (f & 31) << 2;
        unsigned uh, um, ul;
        float4 x = ((const float4*)(Mp + off))[f];
        pack4i(x, uh, um, ul);
        *(unsigned*)&Mh[row*PBI + c4] = uh;
        *(unsigned*)&Mm[row*PBI + c4] = um;
        *(unsigned*)&Ml[row*PBI + c4] = ul;
        x = ((const float4*)(Yp + off))[f];
        pack4i(x, uh, um, ul);
        *(unsigned*)&Yh[row*PBI + c4] = uh;
        *(unsigned*)&Ym[row*PBI + c4] = um;
        *(unsigned*)&Yl[row*PBI + c4] = ul;
    }
    __syncthreads();

    const int lane = t & 63;
    const int w = t >> 6;
    switch (w) {
        case 0:  ns_i8_body16<0>(Mh,Mm,Ml,Yh,Ym,Yl,outM,outY,off,lane,niter); break;
        case 1:  ns_i8_body16<1>(Mh,Mm,Ml,Yh,Ym,Yl,outM,outY,off,lane,niter); break;
        case 2:  ns_i8_body16<2>(Mh,Mm,Ml,Yh,Ym,Yl,outM,outY,off,lane,niter); break;
        case 3:  ns_i8_body16<3>(Mh,Mm,Ml,Yh,Ym,Yl,outM,outY,off,lane,niter); break;
        case 4:  ns_i8_body16<4>(Mh,Mm,Ml,Yh,Ym,Yl,outM,outY,off,lane,niter); break;
        case 5:  ns_i8_body16<5>(Mh,Mm,Ml,Yh,Ym,Yl,outM,outY,off,lane,niter); break;
        case 6:  ns_i8_body16<6>(Mh,Mm,Ml,Yh,Ym,Yl,outM,outY,off,lane,niter); break;
        case 7:  ns_i8_body16<7>(Mh,Mm,Ml,Yh,Ym,Yl,outM,outY,off,lane,niter); break;
        case 8:  ns_i8_body16<8>(Mh,Mm,Ml,Yh,Ym,Yl,outM,outY,off,lane,niter); break;
        case 9:  ns_i8_body16<9>(Mh,Mm,Ml,Yh,Ym,Yl,outM,outY,off,lane,niter); break;
        case 10: ns_i8_body16<10>(Mh,Mm,Ml,Yh,Ym,Yl,outM,outY,off,lane,niter); break;
        case 11: ns_i8_body16<11>(Mh,Mm,Ml,Yh,Ym,Yl,outM,outY,off,lane,niter); break;
        case 12: ns_i8_body16<12>(Mh,Mm,Ml,Yh,Ym,Yl,outM,outY,off,lane,niter); break;
        case 13: ns_i8_body16<13>(Mh,Mm,Ml,Yh,Ym,Yl,outM,outY,off,lane,niter); break;
        case 14: ns_i8_body16<14>(Mh,Mm,Ml,Yh,Ym,Yl,outM,outY,off,lane,niter); break;
        default: ns_i8_body16<15>(Mh,Mm,Ml,Yh,Ym,Yl,outM,outY,off,lane,niter); break;
    }
}

// ============================================================================
// Fallback (ws too small): round-1 parallel Jacobi
// ============================================================================
#define LDA  129
#define NT   512
#define MAX_SWEEPS 14

__global__ __launch_bounds__(NT, 1)
void logeig_jacobi(const float* __restrict__ in, float* __restrict__ out)
{
    __shared__ float A[NM][LDA];
    __shared__ float V[NM][LDA];
    __shared__ float rc[64], rs[64];
    __shared__ float logd[NM];
    __shared__ float roff[NT/64], rdia[NT/64];
    __shared__ int   s_done;

    const int t = threadIdx.x;
    const long long b = blockIdx.x;
    const float* __restrict__ Ain  = in  + (b << 14);
    float* __restrict__       Aout = out + (b << 14);

    for (int k = 0; k < (NM*NM)/NT; ++k) {
        int idx = t + k*NT;
        int i = idx >> 7, j = idx & 127;
        A[i][j] = Ain[idx];
        V[i][j] = (i == j) ? 1.0f : 0.0f;
    }
    __syncthreads();

    for (int sweep = 0; sweep < MAX_SWEEPS; ++sweep) {
        for (int r = 0; r < NM-1; ++r) {
            if (t < 64) {
                int m = t, p, q;
                if (m == 0) { p = NM-1; q = r; }
                else {
                    p = r + m;            if (p >= NM-1) p -= (NM-1);
                    q = r - m + (NM-1);   if (q >= NM-1) q -= (NM-1);
                }
                float app = A[p][p], aqq = A[q][q], apq = A[p][q];
                float c = 1.0f, s = 0.0f;
                if (fabsf(apq) > 1e-12f*(fabsf(app)+fabsf(aqq)) + 1e-32f) {
                    float tau = (aqq - app) * 0.5f / apq;
                    float tt  = 1.0f / (fabsf(tau) + sqrtf(fmaf(tau,tau,1.0f)));
                    tt = (tau < 0.0f) ? -tt : tt;
                    c = rsqrtf(fmaf(tt,tt,1.0f));
                    s = tt * c;
                }
                rc[m] = c; rs[m] = s;
            }
            __syncthreads();
            for (int k = 0; k < (2*64*NM)/NT; ++k) {
                int task = t + k*NT;
                int i   = task & 127;
                int m   = (task >> 7) & 63;
                int isV = task >> 13;
                int p, q;
                if (m == 0) { p = NM-1; q = r; }
                else {
                    p = r + m;            if (p >= NM-1) p -= (NM-1);
                    q = r - m + (NM-1);   if (q >= NM-1) q -= (NM-1);
                }
                float c = rc[m], s = rs[m];
                if (isV == 0) {
                    float x = A[i][p], y = A[i][q];
                    A[i][p] = c*x - s*y;
                    A[i][q] = s*x + c*y;
                } else {
                    float x = V[i][p], y = V[i][q];
                    V[i][p] = c*x - s*y;
                    V[i][q] = s*x + c*y;
                }
            }
            __syncthreads();
            for (int k = 0; k < (64*NM)/NT; ++k) {
                int task = t + k*NT;
                int j = task & 127;
                int m = task >> 7;
                int p, q;
                if (m == 0) { p = NM-1; q = r; }
                else {
                    p = r + m;            if (p >= NM-1) p -= (NM-1);
                    q = r - m + (NM-1);   if (q >= NM-1) q -= (NM-1);
                }
                float c = rc[m], s = rs[m];
                float x = A[p][j], y = A[q][j];
                A[p][j] = c*x - s*y;
                A[q][j] = s*x + c*y;
            }
            __syncthreads();
        }
        float off2 = 0.0f, dia2 = 0.0f;
        for (int k = 0; k < (NM*NM)/NT; ++k) {
            int idx = t + k*NT;
            int i = idx >> 7, j = idx & 127;
            float v = A[i][j];
            if (i == j) dia2 += v*v; else off2 += v*v;
        }
        #pragma unroll
        for (int o = 32; o > 0; o >>= 1) {
            off2 += __shfl_down(off2, o, 64);
            dia2 += __shfl_down(dia2, o, 64);
        }
        if ((t & 63) == 0) { roff[t >> 6] = off2; rdia[t >> 6] = dia2; }
        __syncthreads();
        if (t == 0) {
            float o2 = 0.0f, d2 = 0.0f;
            for (int w = 0; w < NT/64; ++w) { o2 += roff[w]; d2 += rdia[w]; }
            s_done = (o2 <= 1e-13f * d2) ? 1 : 0;
        }
        __syncthreads();
        if (s_done) break;
    }

    if (t < NM) logd[t] = logf(fmaxf(A[t][t], 1e-12f));
    __syncthreads();
    for (int kk = 0; kk < (NM*NM)/NT; ++kk) {
        int idx = t + kk*NT;
        int i = idx >> 7, k = idx & 127;
        A[i][k] = V[i][k] * logd[k];
    }
    __syncthreads();
    {
        int i  = t >> 2;
        int jb = t & 3;
        float acc[32];
        #pragma unroll
        for (int jj = 0; jj < 32; ++jj) acc[jj] = 0.0f;
        for (int kk = 0; kk < NM; ++kk) {
            int k = (kk + jb) & 127;
            float w = A[i][k];
            #pragma unroll
            for (int jj = 0; jj < 32; ++jj)
                acc[jj] = fmaf(w, V[jb*32 + jj][k], acc[jj]);
        }
        #pragma unroll
        for (int jj = 0; jj < 32; ++jj)
            Aout[i*NM + jb*32 + jj] = acc[jj];
    }
}

// ============================================================================
// Host
// ============================================================================
static void cheb_log_power(double lo, double up, int deg, double* p)
{
    const int NC = deg + 1;
    const int MN = 64;
    double mid = 0.5*(lo+up), hw = 0.5*(up-lo);
    double cc[32];
    for (int j = 0; j < NC; ++j) {
        double s = 0.0;
        for (int m = 0; m < MN; ++m) {
            double th = M_PI*(m+0.5)/MN;
            s += log(mid + hw*cos(th)) * cos(j*th);
        }
        cc[j] = 2.0*s/MN;
    }
    double Tp[32] = {0}, Tc[32] = {0}, Tn[32];
    for (int j = 0; j < NC; ++j) p[j] = 0.0;
    Tp[0] = 1.0;  p[0] += 0.5*cc[0];
    Tc[1] = 1.0;  p[1] += cc[1];
    for (int k = 2; k <= deg; ++k) {
        for (int j = 0; j < NC; ++j) Tn[j] = -Tp[j];
        for (int j = 1; j < NC; ++j) Tn[j] += 2.0*Tc[j-1];
        for (int j = 0; j < NC; ++j) { p[j] += cc[k]*Tn[j]; Tp[j] = Tc[j]; Tc[j] = Tn[j]; }
    }
}

extern "C" void kernel_launch(void* const* d_in, const int* in_sizes, int n_in,
                              void* d_out, int out_size, void* d_ws, size_t ws_size,
                              hipStream_t stream) {
    const float* in = (const float*)d_in[0];
    float* out = (float*)d_out;
    const int batch = in_sizes[0] >> 14;                 // 4096
    const size_t matBytes = (size_t)batch * NM * NM * 4; // 256 MB
    const size_t need = matBytes + (size_t)batch * 4;

    if (ws_size < need) {   // fallback
        logeig_jacobi<<<batch, NT, 0, stream>>>(in, out);
        return;
    }

    float* Mbuf = (float*)d_ws;
    float* lns  = (float*)((char*)d_ws + matBytes);

    // --- scaling: s0 = gersh(A); tighten via sqrt(gersh((A/s0)^2)) ---
    scale_kernel<<<batch, 256, 0, stream>>>(in, out, Mbuf, lns);      // out = X0
    gram_tri<<<batch, 512, 0, stream>>>(out, Mbuf);                   // Mbuf = X0^2
    rescale_kernel<<<batch, 256, 0, stream>>>(Mbuf, out, Mbuf, lns);  // out=Mbuf=X

    // --- L1 iters 0-3 (precision-critical): exact 24-bit i8-MFMA ---
    ns_i8<<<batch, 1024, 0, stream>>>(Mbuf, out, Mbuf, out, 4);

    // --- fused MFMA NS segments (schedule {1.5 x(n-3), 1.116, 1, 1}) ---
    ns_fused<<<batch, 1024, 0, stream>>>(Mbuf, out, out, 8);  // L1 iters 4..11
    ns_fused<<<batch, 1024, 0, stream>>>(out,  out, out, 8);  // L2 (M0=Y0)
    ns_fused<<<batch, 1024, 0, stream>>>(out,  out, out, 6);  // L3 (M0=Y0)

    // --- fused Chebyshev-minimax log, deg 8 on [0.25, 1.002] ---
    const double lo = 0.25, up = 1.002;
    const double mid = 0.5*(lo+up), hw = 0.5*(up-lo);
    double p[9];
    cheb_log_power(lo, up, 8, p);

    PolyCoefs pc;
    pc.a  = (float)(p[8]/hw);
    pc.bd = (float)(p[7] - p[8]*mid/hw);
    pc.s1 = (float)(1.0/hw);
    pc.s2 = (float)(mid/hw);
    pc.c0 = (float)p[6]; pc.c1 = (float)p[5]; pc.c2 = (float)p[4];
    pc.c3 = (float)p[3]; pc.c4 = (float)p[2]; pc.c5 = (float)p[1];
    pc.f1 = (float)(8.0/hw);
    pc.f2 = (float)(8.0*mid/hw);
    pc.f3 = (float)(8.0*p[0]);

    poly_fused<<<batch, 1024, 0, stream>>>(out, out, lns, pc);
}